// Round 5
// baseline (339.912 us; speedup 1.0000x reference)
//
#include <hip/hip_runtime.h>

#define L 2048
#define BS 4
#define CIN 32
#define COUT 32
#define HIDN 64
#define KK 8
#define TB 8
#define EPSV 1e-5f
#define QSTR (HIDN*CIN + 8)     // 2056 f16 per Q row (+16B pad)
#define NBLK ((BS*L)/TB)        // 1024 blocks = 256 CUs x 4
#define NPREP 128
#define MAGIC 0x51CAFE17

typedef _Float16 f16;
typedef _Float16 f16x2 __attribute__((ext_vector_type(2)));
typedef _Float16 f16x8 __attribute__((ext_vector_type(8)));
typedef __fp16   h16x2 __attribute__((ext_vector_type(2)));
typedef float    f32x2 __attribute__((ext_vector_type(2)));
typedef float    f32x4 __attribute__((ext_vector_type(4)));

__global__ __launch_bounds__(256, 4) void cc_fused(
    const float* __restrict__ times,
    const float* __restrict__ features,
    const int*   __restrict__ mask,
    const float* __restrict__ W1,
    const float* __restrict__ b1,
    const float* __restrict__ W2,
    const float* __restrict__ b2,
    const float* __restrict__ Wsk,
    const float* __restrict__ bsk,
    const float* __restrict__ gamma,
    const float* __restrict__ beta,
    float* __restrict__ out,
    float* __restrict__ sums,        // 8 shards x 64 (sum[32], sumsq[32])
    int*   __restrict__ init_flag,
    int*   __restrict__ prep_ctr,
    int*   __restrict__ done_ctr,
    f16*   __restrict__ w2h)
{
    // ---- LDS: 32896 + 1024 + 1024 + 4096 = 39040 B -> 4 blocks/CU ----
    __shared__ __align__(16) char s_pool[TB * QSTR * 2];          // 32896
    f16   (*s_Q )[QSTR]     = (f16  (*)[QSTR])    s_pool;
    f16   (*s_te)[KK][CIN]  = (f16  (*)[KK][CIN]) s_pool;         // 4096 (alias)
    float (*s_f )[KK][CIN]  = (float(*)[KK][CIN])(s_pool + 4096); // 8192 (alias)
    float  *s_W1            = (float*)           (s_pool + 12288);// 8192 (alias)
    __shared__ float s_F [TB][CIN];
    __shared__ float s_ft[TB][CIN];
    __shared__ float s_part[4][TB][COUT];   // MFMA partials; later wave LN sums

    const int tid = threadIdx.x;
    const int tl  = tid >> 5;
    const int x   = tid & 31;
    const int bid = blockIdx.x;
    const int bt  = bid * TB + tl;
    const int b   = bt >> 11;
    const int t   = bt & (L - 1);

    // ---- init (block 0): zero shards+ctrs, then publish flag ----
    if (bid == 0) {
        sums[tid] = 0.f; sums[tid + 256] = 0.f;
        if (tid == 0) { *prep_ctr = 0; *done_ctr = 0; }
        __threadfence();
        __syncthreads();
        if (tid == 0)
            __hip_atomic_store(init_flag, MAGIC, __ATOMIC_RELEASE, __HIP_MEMORY_SCOPE_AGENT);
    }

    // ---- prep (blocks 0..127, wave 0): pack one W2 B-fragment ----
    if (bid < NPREP && tid < 64) {
        const int kb = bid >> 1, nt = bid & 1;
        const int m = tid & 15, qd = tid >> 4;
        const float* src = W2 + (kb*32 + qd*8)*32 + nt*16 + m;
        union { f16x8 v8; h16x2 v2[4]; } p;
        #pragma unroll
        for (int jj = 0; jj < 4; jj++)
            p.v2[jj] = __builtin_amdgcn_cvt_pkrtz(src[(2*jj)*32], src[(2*jj+1)*32]);
        *(f16x8*)&w2h[(bid*64 + tid)*8] = p.v8;
        __threadfence();
    }
    if (bid < NPREP && tid == 0) {
        while (__hip_atomic_load(init_flag, __ATOMIC_ACQUIRE, __HIP_MEMORY_SCOPE_AGENT) != MAGIC)
            __builtin_amdgcn_s_sleep(1);
        __hip_atomic_fetch_add(prep_ctr, 1, __ATOMIC_RELEASE, __HIP_MEMORY_SCOPE_AGENT);
    }

    // ---- stage W1 (f32) into LDS, coalesced ----
    {
        const float4* W1v = (const float4*)W1;   // 512 float4
        ((float4*)s_W1)[tid]       = W1v[tid];
        ((float4*)s_W1)[tid + 256] = W1v[tid + 256];
    }

    // ---- stage 1: te/f for all 8 k ----
    const float t_cur = times[b*L + t];
    const int   np_t  = mask[b*L + t];
    const float inv_pos = exp2f(-(float)(x >> 1) * (13.2877123795f / 16.0f));
    float Fx = 0.f;
    for (int k = 0; k < KK; k++) {
        const int idx   = t - (KK - 1) + k;
        const int valid = idx >= 0;
        const int idxc  = valid ? idx : 0;
        const int dm    = valid && np_t && mask[b*L + idxc];
        const float dt  = dm ? (t_cur - times[b*L + idxc]) : 0.f;
        const float r   = dt * inv_pos;
        s_te[tl][k][x]  = (f16)((x & 1) ? __cosf(r) : __sinf(r));
        const float fv  = dm ? features[(b*L + idxc)*CIN + x] : 0.f;
        s_f[tl][k][x]   = fv;
        Fx += fv;
    }
    s_F [tl][x] = Fx;
    s_ft[tl][x] = features[(b*L + t)*CIN + x];
    __syncthreads();                               // B1

    // ---- pack W1 columns x, x+32 to f16 pairs (from LDS f32) ----
    union UH { f16x8 v8[4]; f16x2 d2[16]; h16x2 w2_[16]; };
    UH wa, wb;
    #pragma unroll
    for (int i2 = 0; i2 < 16; i2++) {
        wa.w2_[i2] = __builtin_amdgcn_cvt_pkrtz(s_W1[(2*i2)*HIDN + x],
                                                s_W1[(2*i2+1)*HIDN + x]);
        wb.w2_[i2] = __builtin_amdgcn_cvt_pkrtz(s_W1[(2*i2)*HIDN + x + 32],
                                                s_W1[(2*i2+1)*HIDN + x + 32]);
    }
    const float b1a = b1[x], b1b = b1[x + 32];

    // ---- phase A: rank-8 Q build (constant reg indices only) ----
    f32x2 q0[16], q1[16];
    #pragma unroll
    for (int c = 0; c < 16; c++) { q0[c] = (f32x2){0.f,0.f}; q1[c] = (f32x2){0.f,0.f}; }

    for (int k = 0; k < KK; k++) {
        union UT { f16x8 v8[4]; f16x2 d2[16]; } te;
        union UF { f32x4 v4[8]; f32x2 d2[16]; } ff;
        #pragma unroll
        for (int i = 0; i < 4; i++) te.v8[i] = ((const f16x8*)&s_te[tl][k][0])[i];
        #pragma unroll
        for (int i = 0; i < 8; i++) ff.v4[i] = ((const f32x4*)&s_f[tl][k][0])[i];

        float ha = b1a, hb = b1b;
        #pragma unroll
        for (int i2 = 0; i2 < 16; i2++) {
            ha = __builtin_amdgcn_fdot2(te.d2[i2], wa.d2[i2], ha, false);
            hb = __builtin_amdgcn_fdot2(te.d2[i2], wb.d2[i2], hb, false);
        }
        ha = fmaxf(ha, 0.f); hb = fmaxf(hb, 0.f);
        const f32x2 h2a = {ha, ha}, h2b = {hb, hb};
        #pragma unroll
        for (int c = 0; c < 16; c++) {
            q0[c] = h2a * ff.d2[c] + q0[c];
            q1[c] = h2b * ff.d2[c] + q1[c];
        }
    }
    __syncthreads();                               // B2 (te/f/W1 dead; s_Q live)

    // ---- pack Q to f16 LDS ----
    #pragma unroll
    for (int cj = 0; cj < 4; cj++) {
        union { f16x8 v8; h16x2 v2[4]; } p0, p1;
        #pragma unroll
        for (int j = 0; j < 4; j++) {
            p0.v2[j] = __builtin_amdgcn_cvt_pkrtz(q0[cj*4 + j][0], q0[cj*4 + j][1]);
            p1.v2[j] = __builtin_amdgcn_cvt_pkrtz(q1[cj*4 + j][0], q1[cj*4 + j][1]);
        }
        *(f16x8*)&s_Q[tl][x*32 + cj*8]        = p0.v8;
        *(f16x8*)&s_Q[tl][(x + 32)*32 + cj*8] = p1.v8;
    }

    // extras: b_skip + feat@Wsk + F@b2rows
    float ex = bsk[x];
    #pragma unroll
    for (int c = 0; c < CIN; c++) ex = fmaf(s_ft[tl][c], Wsk[c*COUT + x], ex);
    #pragma unroll
    for (int c = 0; c < CIN; c++) ex = fmaf(s_F [tl][c], b2 [c*COUT + x], ex);

    // gate on W2 fragments ready, then barrier doubles as s_Q publish
    if (tid == 0) {
        while (__hip_atomic_load(prep_ctr, __ATOMIC_ACQUIRE, __HIP_MEMORY_SCOPE_AGENT) != NPREP)
            __builtin_amdgcn_s_sleep(1);
    }
    __syncthreads();                               // B3

    // ---- phase B: MFMA, K=2048 split over 4 waves ----
    {
        const int wv   = tid >> 6;
        const int lane = tid & 63;
        const int m    = lane & 15, qd = lane >> 4;
        f32x4 C0 = {0.f,0.f,0.f,0.f}, C1 = {0.f,0.f,0.f,0.f};
        #pragma unroll 4
        for (int kb = wv*16; kb < wv*16 + 16; kb++) {
            const f16x8 a   = *(const f16x8*)&s_Q[m & 7][kb*32 + qd*8];
            const f16x8 bf0 = ((const f16x8*)w2h)[(kb*2 + 0)*64 + lane];
            const f16x8 bf1 = ((const f16x8*)w2h)[(kb*2 + 1)*64 + lane];
            C0 = __builtin_amdgcn_mfma_f32_16x16x32_f16(a, bf0, C0, 0, 0, 0);
            C1 = __builtin_amdgcn_mfma_f32_16x16x32_f16(a, bf1, C1, 0, 0, 0);
        }
        if (qd < 2) {
            #pragma unroll
            for (int r = 0; r < 4; r++) {
                s_part[wv][qd*4 + r][m]      = C0[r];
                s_part[wv][qd*4 + r][16 + m] = C1[r];
            }
        }
    }
    __syncthreads();                               // B4

    float val = ex;
    #pragma unroll
    for (int w = 0; w < 4; w++) val += s_part[w][tl][x];
    __syncthreads();                               // B5 (s_part reads done)

    // ---- block LN sums: wave shuffle (lanes x and x+32 share channel) ----
    const float vs = val + __shfl_xor(val, 32);
    const float vq = val*val + __shfl_xor(val*val, 32);
    {
        const int wv = tid >> 6, lane = tid & 63;
        if (lane < 32) { s_part[wv][0][lane] = vs; s_part[wv][1][lane] = vq; }
    }
    __syncthreads();                               // B6
    if (tid < 32) {
        float s1 = 0.f, s2 = 0.f;
        #pragma unroll
        for (int w = 0; w < 4; w++) { s1 += s_part[w][0][x]; s2 += s_part[w][1][x]; }
        float* shard = sums + (bid & 7) * 64;
        atomicAdd(&shard[x],      s1);
        atomicAdd(&shard[32 + x], s2);
    }
    __threadfence();
    if (tid == 0) {
        __hip_atomic_fetch_add(done_ctr, 1, __ATOMIC_RELEASE, __HIP_MEMORY_SCOPE_AGENT);
        while (__hip_atomic_load(done_ctr, __ATOMIC_ACQUIRE, __HIP_MEMORY_SCOPE_AGENT) != NBLK)
            __builtin_amdgcn_s_sleep(8);
    }
    __syncthreads();                               // B7

    // ---- normalize from registers, single out write ----
    float s1 = 0.f, s2 = 0.f;
    #pragma unroll
    for (int s = 0; s < 8; s++) {
        s1 += __hip_atomic_load(&sums[s*64 + x],      __ATOMIC_RELAXED, __HIP_MEMORY_SCOPE_AGENT);
        s2 += __hip_atomic_load(&sums[s*64 + 32 + x], __ATOMIC_RELAXED, __HIP_MEMORY_SCOPE_AGENT);
    }
    const float n    = (float)(BS * L);
    const float mean = s1 / n;
    const float var  = s2 / n - mean * mean;
    out[(b*L + t)*COUT + x] = gamma[x] * (val - mean) * rsqrtf(var + EPSV) + beta[x];
}

extern "C" void kernel_launch(void* const* d_in, const int* in_sizes, int n_in,
                              void* d_out, int out_size, void* d_ws, size_t ws_size,
                              hipStream_t stream) {
    const float* times    = (const float*)d_in[0];
    const float* features = (const float*)d_in[1];
    const int*   mask     = (const int*)  d_in[2];
    const float* W1       = (const float*)d_in[3];
    const float* b1       = (const float*)d_in[4];
    const float* W2       = (const float*)d_in[5];
    const float* b2       = (const float*)d_in[6];
    const float* Wsk      = (const float*)d_in[7];
    const float* bsk      = (const float*)d_in[8];
    const float* gamma    = (const float*)d_in[9];
    const float* beta     = (const float*)d_in[10];
    float* out  = (float*)d_out;

    float* sums      = (float*)d_ws;                    // 512 floats (8 shards)
    int*   init_flag = (int*)((char*)d_ws + 2048);
    int*   prep_ctr  = (int*)((char*)d_ws + 2052);
    int*   done_ctr  = (int*)((char*)d_ws + 2056);
    f16*   w2h       = (f16*)((char*)d_ws + 4096);      // 128 KB

    cc_fused<<<NBLK, 256, 0, stream>>>(times, features, mask, W1, b1, W2, b2,
                                       Wsk, bsk, gamma, beta, out,
                                       sums, init_flag, prep_ctr, done_ctr, w2h);
}

// Round 6
// 95.517 us; speedup vs baseline: 3.5586x; 3.5586x over previous
//
#include <hip/hip_runtime.h>

#define L 2048
#define BS 4
#define CIN 32
#define COUT 32
#define HIDN 64
#define KK 8
#define TB 8
#define EPSV 1e-5f
#define QSTR (HIDN*CIN + 8)   // 2056 f16 row (+16B pad): a-frag reads conflict-free

typedef _Float16 f16;
typedef _Float16 f16x2 __attribute__((ext_vector_type(2)));
typedef _Float16 f16x8 __attribute__((ext_vector_type(8)));
typedef __fp16   h16x2 __attribute__((ext_vector_type(2)));
typedef float    f32x2 __attribute__((ext_vector_type(2)));
typedef float    f32x4 __attribute__((ext_vector_type(4)));

// blocks 0..127: W2 -> MFMA B-fragments (f16). block 0 zeroes the 8 LN shards.
// block 128: W1 -> per-column f16 pairs.
__global__ __launch_bounds__(64) void prep(const float* __restrict__ W2,
                                           const float* __restrict__ W1,
                                           f16* __restrict__ w2h,
                                           f16* __restrict__ w1p,
                                           float* __restrict__ sums) {
    const int f    = blockIdx.x;
    const int lane = threadIdx.x;
    if (f == 128) {
        #pragma unroll
        for (int i2 = 0; i2 < 16; i2++) {
            w1p[lane*32 + i2*2 + 0] = (f16)W1[(2*i2 + 0)*HIDN + lane];
            w1p[lane*32 + i2*2 + 1] = (f16)W1[(2*i2 + 1)*HIDN + lane];
        }
        return;
    }
    if (f == 0) {
        #pragma unroll
        for (int j = 0; j < 8; j++) sums[j*64 + lane] = 0.f;
    }
    const int kb = f >> 1, nt = f & 1;
    const int m = lane & 15, qd = lane >> 4;
    #pragma unroll
    for (int j = 0; j < 8; j++)
        w2h[(f*64 + lane)*8 + j] = (f16)W2[(kb*32 + qd*8 + j)*32 + nt*16 + m];
}

__global__ __launch_bounds__(256, 4) void cc_main(
    const float* __restrict__ times,
    const float* __restrict__ features,
    const int*   __restrict__ mask,
    const float* __restrict__ b1,
    const float* __restrict__ b2,
    const float* __restrict__ Wsk,
    const float* __restrict__ bsk,
    const f16*   __restrict__ w2h,
    const f16*   __restrict__ w1p,
    float* __restrict__ out,
    float* __restrict__ sums)        // 8 shards x 64
{
    // 32896 + 1024 + 1024 + 4096 = 39040 B -> 4 blocks/CU
    __shared__ __align__(16) char s_pool[TB * QSTR * 2];
    f16   (*s_Q )[QSTR]     = (f16  (*)[QSTR])    s_pool;
    f16   (*s_te)[KK][CIN]  = (f16  (*)[KK][CIN]) s_pool;          // alias, 4 KB
    float (*s_f )[KK][CIN]  = (float(*)[KK][CIN])(s_pool + 4096);  // alias, 8 KB
    __shared__ float s_F [TB][CIN];
    __shared__ float s_ft[TB][CIN];
    __shared__ float s_part[4][TB][COUT];

    const int tid = threadIdx.x;
    const int tl  = tid >> 5;
    const int x   = tid & 31;
    const int bt  = blockIdx.x * TB + tl;
    const int b   = bt >> 11;
    const int t   = bt & (L - 1);

    // ---- hoisted weight loads (overlap stage-1 latency) ----
    union UH { f16x8 v8[4]; f16x2 d2[16]; } wa, wb;
    #pragma unroll
    for (int i = 0; i < 4; i++) {
        wa.v8[i] = ((const f16x8*)(w1p + x*32))[i];
        wb.v8[i] = ((const f16x8*)(w1p + (x + 32)*32))[i];
    }
    const float b1a = b1[x], b1b = b1[x + 32];

    // ---- stage 1: all loads unconditional & independent ----
    const float t_cur = times[b*L + t];
    const int   np_t  = mask[b*L + t];
    float tv[KK], fr[KK];
    int   mv[KK];
    #pragma unroll
    for (int k = 0; k < KK; k++) {
        const int idx  = t - (KK - 1) + k;
        const int idxc = idx > 0 ? idx : 0;
        tv[k] = times[b*L + idxc];
        mv[k] = mask[b*L + idxc];
        fr[k] = features[(b*L + idxc)*CIN + x];
    }
    const float inv_pos = exp2f(-(float)(x >> 1) * (13.2877123795f / 16.0f));
    float Fx = 0.f;
    #pragma unroll
    for (int k = 0; k < KK; k++) {
        const int dm  = (t - (KK - 1) + k >= 0) && np_t && mv[k];
        const float r = (t_cur - tv[k]) * inv_pos;   // finite even when masked
        s_te[tl][k][x] = (f16)((x & 1) ? __cosf(r) : __sinf(r));
        const float fv = dm ? fr[k] : 0.f;           // all masking folds into f
        s_f[tl][k][x] = fv;
        Fx += fv;
    }
    s_F [tl][x] = Fx;
    s_ft[tl][x] = features[(b*L + t)*CIN + x];
    __syncthreads();                                  // B1

    // ---- phase A: rank-8 Q build; 4 independent fdot2 chains ----
    f32x2 q0[16], q1[16];
    #pragma unroll
    for (int c = 0; c < 16; c++) { q0[c] = (f32x2){0.f,0.f}; q1[c] = (f32x2){0.f,0.f}; }

    #pragma unroll
    for (int k = 0; k < KK; k++) {
        union UT { f16x8 v8[4]; f16x2 d2[16]; } te;
        union UF { f32x4 v4[8]; f32x2 d2[16]; } ff;
        #pragma unroll
        for (int i = 0; i < 4; i++) te.v8[i] = ((const f16x8*)&s_te[tl][k][0])[i];
        #pragma unroll
        for (int i = 0; i < 8; i++) ff.v4[i] = ((const f32x4*)&s_f[tl][k][0])[i];

        float a0 = 0.f, a1 = 0.f, a2 = 0.f, a3 = 0.f;
        float c0 = 0.f, c1 = 0.f, c2 = 0.f, c3 = 0.f;
        #pragma unroll
        for (int g = 0; g < 4; g++) {
            a0 = __builtin_amdgcn_fdot2(te.d2[g*4+0], wa.d2[g*4+0], a0, false);
            a1 = __builtin_amdgcn_fdot2(te.d2[g*4+1], wa.d2[g*4+1], a1, false);
            a2 = __builtin_amdgcn_fdot2(te.d2[g*4+2], wa.d2[g*4+2], a2, false);
            a3 = __builtin_amdgcn_fdot2(te.d2[g*4+3], wa.d2[g*4+3], a3, false);
            c0 = __builtin_amdgcn_fdot2(te.d2[g*4+0], wb.d2[g*4+0], c0, false);
            c1 = __builtin_amdgcn_fdot2(te.d2[g*4+1], wb.d2[g*4+1], c1, false);
            c2 = __builtin_amdgcn_fdot2(te.d2[g*4+2], wb.d2[g*4+2], c2, false);
            c3 = __builtin_amdgcn_fdot2(te.d2[g*4+3], wb.d2[g*4+3], c3, false);
        }
        const float ha = fmaxf(((a0 + a1) + (a2 + a3)) + b1a, 0.f);
        const float hb = fmaxf(((c0 + c1) + (c2 + c3)) + b1b, 0.f);
        const f32x2 h2a = {ha, ha}, h2b = {hb, hb};
        #pragma unroll
        for (int c = 0; c < 16; c++) {
            q0[c] = h2a * ff.d2[c] + q0[c];           // v_pk_fma_f32
            q1[c] = h2b * ff.d2[c] + q1[c];
        }
    }
    __syncthreads();                                  // B2 (te/f dead, s_Q live)

    // ---- pack Q to f16 LDS, XOR-swizzled chunks: ch = (h*4+cj)^(h&7) ----
    const int sw = x & 7;                             // (x+32)&7 == x&7
    #pragma unroll
    for (int cj = 0; cj < 4; cj++) {
        union { f16x8 v8; h16x2 v2[4]; } p0, p1;
        #pragma unroll
        for (int j = 0; j < 4; j++) {
            p0.v2[j] = __builtin_amdgcn_cvt_pkrtz(q0[cj*4 + j][0], q0[cj*4 + j][1]);
            p1.v2[j] = __builtin_amdgcn_cvt_pkrtz(q1[cj*4 + j][0], q1[cj*4 + j][1]);
        }
        const int ch0 = ((x*4 + cj) ^ sw);
        const int ch1 = (((x + 32)*4 + cj) ^ sw);
        *(f16x8*)&s_Q[tl][ch0*8] = p0.v8;
        *(f16x8*)&s_Q[tl][ch1*8] = p1.v8;
    }

    // extras: b_skip + feat@Wsk + F@b2rows (overlaps the barrier)
    float ex = bsk[x];
    #pragma unroll
    for (int c = 0; c < CIN; c++) ex = fmaf(s_ft[tl][c], Wsk[c*COUT + x], ex);
    #pragma unroll
    for (int c = 0; c < CIN; c++) ex = fmaf(s_F [tl][c], b2 [c*COUT + x], ex);
    __syncthreads();                                  // B3 (publish s_Q)

    // ---- phase B: MFMA, K=2048 split over 4 waves ----
    {
        const int wv   = tid >> 6;
        const int lane = tid & 63;
        const int m    = lane & 15, qd = lane >> 4;
        const int row  = m & 7;
        f32x4 C0 = {0.f,0.f,0.f,0.f}, C1 = {0.f,0.f,0.f,0.f};
        #pragma unroll 4
        for (int kb = wv*16; kb < wv*16 + 16; kb++) {
            const int ch = ((kb*4 + qd) ^ (kb & 7));
            const f16x8 a   = *(const f16x8*)&s_Q[row][ch*8];
            const f16x8 bf0 = ((const f16x8*)w2h)[(kb*2 + 0)*64 + lane];
            const f16x8 bf1 = ((const f16x8*)w2h)[(kb*2 + 1)*64 + lane];
            C0 = __builtin_amdgcn_mfma_f32_16x16x32_f16(a, bf0, C0, 0, 0, 0);
            C1 = __builtin_amdgcn_mfma_f32_16x16x32_f16(a, bf1, C1, 0, 0, 0);
        }
        if (qd < 2) {
            #pragma unroll
            for (int r = 0; r < 4; r++) {
                s_part[wv][qd*4 + r][m]      = C0[r];
                s_part[wv][qd*4 + r][16 + m] = C1[r];
            }
        }
    }
    __syncthreads();                                  // B4

    float val = ex;
    #pragma unroll
    for (int w = 0; w < 4; w++) val += s_part[w][tl][x];
    out[(b*L + t)*COUT + x] = val;

    // block LN sums (s_F/s_ft dead after extras; B4 separates)
    s_F [tl][x] = val;
    s_ft[tl][x] = val * val;
    __syncthreads();                                  // B5
    if (tid < 32) {
        float s1 = 0.f, s2 = 0.f;
        #pragma unroll
        for (int j = 0; j < TB; j++) { s1 += s_F[j][x]; s2 += s_ft[j][x]; }
        float* shard = sums + (blockIdx.x & 7) * 64;
        atomicAdd(&shard[x],      s1);
        atomicAdd(&shard[32 + x], s2);
    }
}

__global__ __launch_bounds__(256) void cc_norm(
    float4* __restrict__ out, const float* __restrict__ sums,
    const float* __restrict__ gamma, const float* __restrict__ beta)
{
    const int i  = blockIdx.x * 256 + threadIdx.x;    // float4 index
    const int o0 = (i & 7) * 4;
    const float n = (float)(BS * L);
    float4 v = out[i], r;
    float* vp = &v.x; float* rp = &r.x;
    #pragma unroll
    for (int j = 0; j < 4; j++) {
        const int o = o0 + j;
        float s1 = 0.f, s2 = 0.f;
        #pragma unroll
        for (int s = 0; s < 8; s++) { s1 += sums[s*64 + o]; s2 += sums[s*64 + 32 + o]; }
        const float mean = s1 / n;
        const float var  = s2 / n - mean * mean;
        rp[j] = gamma[o] * (vp[j] - mean) * rsqrtf(var + EPSV) + beta[o];
    }
    out[i] = r;
}

extern "C" void kernel_launch(void* const* d_in, const int* in_sizes, int n_in,
                              void* d_out, int out_size, void* d_ws, size_t ws_size,
                              hipStream_t stream) {
    const float* times    = (const float*)d_in[0];
    const float* features = (const float*)d_in[1];
    const int*   mask     = (const int*)  d_in[2];
    const float* W1       = (const float*)d_in[3];
    const float* b1       = (const float*)d_in[4];
    const float* W2       = (const float*)d_in[5];
    const float* b2       = (const float*)d_in[6];
    const float* Wsk      = (const float*)d_in[7];
    const float* bsk      = (const float*)d_in[8];
    const float* gamma    = (const float*)d_in[9];
    const float* beta     = (const float*)d_in[10];
    float* out  = (float*)d_out;
    float* sums = (float*)d_ws;                          // 512 floats (8 shards)
    f16*   w2h  = (f16*)((char*)d_ws + 4096);            // 128 KB
    f16*   w1p  = (f16*)((char*)d_ws + 4096 + 131072);   // 4 KB

    prep<<<129, 64, 0, stream>>>(W2, W1, w2h, w1p, sums);
    cc_main<<<(BS*L)/TB, 256, 0, stream>>>(times, features, mask, b1,
                                           b2, Wsk, bsk, w2h, w1p, out, sums);
    cc_norm<<<(BS*L*COUT)/(4*256), 256, 0, stream>>>((float4*)out, sums, gamma, beta);
}